// Round 2
// 1675.413 us; speedup vs baseline: 1.3765x; 1.3765x over previous
//
#include <hip/hip_runtime.h>
#include <hip/hip_bf16.h>

constexpr float EPS = 1e-5f;

typedef __attribute__((ext_vector_type(8))) short short8;   // 8 bf16 = 4 VGPRs
typedef __attribute__((ext_vector_type(4))) float floatx4;  // MFMA C/D

// ---------------------------------------------------------------------------
// K0: one-time prep. WcT[p][k][d][cin] bf16, 16B-chunk-swizzled so k2 can
// stage it to LDS with a LINEAR global_load_lds copy and read B fragments
// conflict-free: stored chunk sc of row d holds logical chunk sc ^ (d&7).
// 108 blocks x 256 thr, ~5us.
// ---------------------------------------------------------------------------
__global__ __launch_bounds__(256) void k0_wct(
    const float* __restrict__ Wc, __hip_bfloat16* __restrict__ wct)
{
    __shared__ float T[64][65];
    const int pk = blockIdx.x;                   // p*27+k
    const float* src = Wc + (size_t)pk * 4096;   // [cin][d] fp32
    __hip_bfloat16* dst = wct + (size_t)pk * 4096;
    const int t = threadIdx.x;
    #pragma unroll
    for (int e = 0; e < 16; e++) {
        const int idx = t + 256 * e;             // cin = idx>>6, d = idx&63
        T[idx >> 6][idx & 63] = src[idx];
    }
    __syncthreads();
    #pragma unroll
    for (int e = 0; e < 16; e++) {
        const int idx = t + 256 * e;             // out: row d, stored pos q
        const int d = idx >> 6, q = idx & 63;
        const int sc = q >> 3, j = q & 7;
        const int cin = ((sc ^ (d & 7)) << 3) | j;
        dst[idx] = __float2bfloat16(T[cin][d]);
    }
}

// ---------------------------------------------------------------------------
// K1: h[n,256](bf16) = x[n,256] @ Wl[p][256,64] (+ bl). unchanged.
// ---------------------------------------------------------------------------
__global__ __launch_bounds__(256) void k1_gemm_h(
    const float* __restrict__ x, const float* __restrict__ Wl,
    const float* __restrict__ bl, __hip_bfloat16* __restrict__ hb, int n)
{
    __shared__ float As[16][68];
    __shared__ float Bs[16][64];
    const int row0 = blockIdx.x * 64;
    const int pb   = blockIdx.y;
    const int t    = threadIdx.x;
    const int tx = t & 15, ty = t >> 4;
    const int ka = t & 15, ma = t >> 4;
    const int nb = t & 63, kb = t >> 6;
    const float* Wp = Wl + (size_t)pb * 256 * 64;
    float acc[4][4] = {};

    for (int k0 = 0; k0 < 256; k0 += 16) {
        #pragma unroll
        for (int i = 0; i < 4; i++)
            As[ka][ma + 16 * i] = x[(size_t)(row0 + ma + 16 * i) * 256 + k0 + ka];
        #pragma unroll
        for (int i = 0; i < 4; i++)
            Bs[kb + 4 * i][nb] = Wp[(size_t)(k0 + kb + 4 * i) * 64 + nb];
        __syncthreads();
        #pragma unroll
        for (int kk = 0; kk < 16; kk++) {
            float a[4], b[4];
            #pragma unroll
            for (int i = 0; i < 4; i++) a[i] = As[kk][ty * 4 + i];
            #pragma unroll
            for (int j = 0; j < 4; j++) b[j] = Bs[kk][tx * 4 + j];
            #pragma unroll
            for (int i = 0; i < 4; i++)
                #pragma unroll
                for (int j = 0; j < 4; j++)
                    acc[i][j] += a[i] * b[j];
        }
        __syncthreads();
    }
    #pragma unroll
    for (int i = 0; i < 4; i++) {
        const int r = row0 + ty * 4 + i;
        #pragma unroll
        for (int j = 0; j < 4; j++) {
            const int c = pb * 64 + tx * 4 + j;
            hb[(size_t)r * 256 + c] = __float2bfloat16(acc[i][j] + bl[c]);
        }
    }
}

// ---------------------------------------------------------------------------
// K2: gather conv. 128 output rows/block, 512 thr (8 waves), p = blockIdx.y.
// Per k: W tile staged by async global_load_lds (linear, pre-swizzled source,
// double-buffered: stage k+1 overlaps compute k); pair list for [row0,upper)
// is the contiguous run [spos,epos) of the sorted out_idx -> trivial compact;
// upper is clamped to n so sentinel padding (value n) is NEVER counted
// (unclamped, the last block's cnt explodes -> OOB csrc -> wild gathers).
// A rows gathered straight from global hb (sentinel row n = zeros) into regs;
// bf16 MFMA 16x16x32; C scattered into fp32 LDS Acc; one barrier per k.
// ---------------------------------------------------------------------------
__global__ __launch_bounds__(512) void k2_conv(
    const __hip_bfloat16* __restrict__ hb, const __hip_bfloat16* __restrict__ wct,
    const int* __restrict__ in_idx, const int* __restrict__ out_idx,
    float* __restrict__ accum, int n, int M)
{
    __shared__ __align__(16) __hip_bfloat16 Ws[2][4096];  // [d][64] swizzled chunks
    __shared__ float Acc[128][66];                        // stride 66: float2-aligned
    __shared__ int csrc[2][128];
    __shared__ int cdst[2][128];
    __shared__ int spos_s[27];
    __shared__ int epos_s[27];

    const int p    = blockIdx.y;
    const int t    = threadIdx.x;
    const int lane = t & 63;
    const int wv   = t >> 6;
    const int mrow = lane & 15;
    const int quad = lane >> 4;

    // bijective XCD-chunked swizzle of the row-block index (nwg % 8 != 0 safe)
    const int nwg = gridDim.x;
    const int qq = nwg >> 3, rr = nwg & 7;
    const int xcd = blockIdx.x & 7, ii = blockIdx.x >> 3;
    const int bx = (xcd < rr ? xcd * (qq + 1) : rr * (qq + 1) + (xcd - rr) * qq) + ii;
    const int row0 = bx << 7;

    for (int i = t; i < 128 * 66; i += 512) ((float*)Acc)[i] = 0.0f;

    if (t < 54) {
        const int kk = (t < 27) ? t : t - 27;
        const int upper = (row0 + 128 > n) ? n : row0 + 128;  // exclude sentinels (==n)
        const int target = (t < 27) ? row0 : upper;
        const int* oi = out_idx + (size_t)(p * 27 + kk) * M;
        int lo = 0, hi = M;
        while (lo < hi) {
            const int mid = (lo + hi) >> 1;
            if (oi[mid] < target) lo = mid + 1; else hi = mid;
        }
        if (t < 27) spos_s[kk] = lo; else epos_s[kk] = lo;
    }
    __syncthreads();

#define STAGE(buf, kk) do {                                                         \
        const char* gs_ = (const char*)wct + (((size_t)(p * 27 + (kk))) << 13)      \
                          + (wv << 10) + (lane << 4);                               \
        __builtin_amdgcn_global_load_lds(                                           \
            (const __attribute__((address_space(1))) void*)gs_,                     \
            (__attribute__((address_space(3))) void*)((char*)&Ws[buf][0] + (wv << 10)), \
            16, 0, 0);                                                              \
    } while (0)

#define COMPACT(buf, kk) do {                                                       \
        if (t < 128) {                                                              \
            const int sp_ = spos_s[kk];                                             \
            int cn_ = epos_s[kk] - sp_;                                             \
            if (cn_ > 128) cn_ = 128;  /* defensive: cannot exceed 128 rows */      \
            const size_t base_ = (size_t)(p * 27 + (kk)) * M + sp_;                 \
            int v_ = n;                                                             \
            if (t < cn_) {                                                          \
                v_ = in_idx[base_ + t];                                             \
                cdst[buf][t] = out_idx[base_ + t] - row0;                           \
            }                                                                       \
            csrc[buf][t] = v_;                                                      \
        }                                                                           \
    } while (0)

    STAGE(0, 0);
    COMPACT(0, 0);
    __syncthreads();

    for (int k = 0; k < 27; k++) {
        const int cur = k & 1;
        if (k < 26) { STAGE(cur ^ 1, k + 1); COMPACT(cur ^ 1, k + 1); }

        int cnt = epos_s[k] - spos_s[k];
        if (cnt > 128) cnt = 128;          // defensive clamp (matches COMPACT)
        const int tids = ((cnt + 15) >> 4) << 2;   // TR*4, TR in 1..8
        const int bsw  = (quad ^ (mrow & 7)) << 3; // stored-chunk element offset

        for (int tid = wv; tid < tids; tid += 8) {
            const int tr = tid >> 2, tc = tid & 3;
            const int srow = csrc[cur][(tr << 4) + mrow];
            const __hip_bfloat16* ar = hb + ((size_t)srow << 8) + (p << 6) + (quad << 3);
            const short8 a0 = *(const short8*)ar;
            const short8 a1 = *(const short8*)(ar + 32);
            const int brow = ((tc << 4) + mrow) << 6;
            const short8 b0 = *(const short8*)(Ws[cur] + brow + bsw);
            const short8 b1 = *(const short8*)(Ws[cur] + brow + (bsw ^ 32));
            floatx4 c = {0.f, 0.f, 0.f, 0.f};
            c = __builtin_amdgcn_mfma_f32_16x16x32_bf16(a0, b0, c, 0, 0, 0);
            c = __builtin_amdgcn_mfma_f32_16x16x32_bf16(a1, b1, c, 0, 0, 0);
            #pragma unroll
            for (int rg = 0; rg < 4; rg++) {
                const int m = (tr << 4) + (quad << 2) + rg;
                if (m < cnt)
                    Acc[cdst[cur][m]][(tc << 4) + mrow] += c[rg];
            }
        }
        __syncthreads();  // Acc/Ws[cur]/csrc[cur] reads done; vmcnt drained
    }

    // write the block's 128x64 patch (written exactly once, rows < n)
    for (int i = t; i < 128 * 32; i += 512) {
        const int r = i >> 5, cc = (i & 31) << 1;
        const int gr = row0 + r;
        if (gr < n)
            *(float2*)(accum + (size_t)gr * 256 + (p << 6) + cc) =
                *(const float2*)&Acc[r][cc];
    }
#undef STAGE
#undef COMPACT
}

// ---------------------------------------------------------------------------
// K3a: per-column sum / sumsq over accum[n,256].
// ---------------------------------------------------------------------------
__global__ __launch_bounds__(256) void k3_stats(
    const float* __restrict__ acc, float* __restrict__ ssum,
    float* __restrict__ ssq, int n)
{
    const int t = threadIdx.x;
    float s = 0.f, s2 = 0.f;
    for (int r = blockIdx.x; r < n; r += gridDim.x) {
        const float v = acc[(size_t)r * 256 + t];
        s += v;
        s2 += v * v;
    }
    atomicAdd(&ssum[t], s);
    atomicAdd(&ssq[t], s2);
}

__global__ void k3_final(
    const float* __restrict__ ssum, const float* __restrict__ ssq,
    const float* __restrict__ gamma, const float* __restrict__ beta,
    float* __restrict__ scale, float* __restrict__ shift, int n)
{
    const int t = threadIdx.x;  // 256
    const float inv_n = 1.0f / (float)n;
    const float mu  = ssum[t] * inv_n;
    const float var = ssq[t] * inv_n - mu * mu;
    const float sc  = gamma[t] * rsqrtf(var + EPS);
    scale[t] = sc;
    shift[t] = beta[t] - mu * sc;
}

// ---------------------------------------------------------------------------
// K4: io[n,256] = relu(io*scale+shift) @ W2 + b2 + x, IN-PLACE on d_out.
// ---------------------------------------------------------------------------
__global__ __launch_bounds__(256) void k4_gemm_out(
    float* __restrict__ io, const float* __restrict__ W2,
    const float* __restrict__ b2, const float* __restrict__ x,
    const float* __restrict__ scale, const float* __restrict__ shift, int n)
{
    __shared__ float As[16][68];
    __shared__ float Bs[16][260];
    __shared__ float sc[256], sh[256];
    const int row0 = blockIdx.x * 64;
    const int t = threadIdx.x;
    const int tx = t & 15, ty = t >> 4;
    const int ka = t & 15, ma = t >> 4;
    float acc[4][16] = {};

    sc[t] = scale[t];
    sh[t] = shift[t];
    __syncthreads();

    for (int k0 = 0; k0 < 256; k0 += 16) {
        const float s_k = sc[k0 + ka];
        const float h_k = sh[k0 + ka];
        #pragma unroll
        for (int i = 0; i < 4; i++) {
            const float v = io[(size_t)(row0 + ma + 16 * i) * 256 + k0 + ka];
            As[ka][ma + 16 * i] = fmaxf(v * s_k + h_k, 0.0f);
        }
        #pragma unroll
        for (int r = 0; r < 16; r++)
            Bs[r][t] = W2[(size_t)(k0 + r) * 256 + t];
        __syncthreads();
        #pragma unroll
        for (int kk = 0; kk < 16; kk++) {
            float a[4], b[16];
            #pragma unroll
            for (int i = 0; i < 4; i++) a[i] = As[kk][ty * 4 + i];
            #pragma unroll
            for (int j = 0; j < 16; j++) b[j] = Bs[kk][j * 16 + tx];
            #pragma unroll
            for (int i = 0; i < 4; i++)
                #pragma unroll
                for (int j = 0; j < 16; j++)
                    acc[i][j] += a[i] * b[j];
        }
        __syncthreads();
    }
    #pragma unroll
    for (int i = 0; i < 4; i++) {
        const size_t r = row0 + ty * 4 + i;
        #pragma unroll
        for (int j = 0; j < 16; j++) {
            const int c = j * 16 + tx;
            io[r * 256 + c] = acc[i][j] + b2[c] + x[r * 256 + c];
        }
    }
}

// ---------------------------------------------------------------------------
extern "C" void kernel_launch(void* const* d_in, const int* in_sizes, int n_in,
                              void* d_out, int out_size, void* d_ws, size_t ws_size,
                              hipStream_t stream)
{
    const float* x     = (const float*)d_in[0];
    const float* Wl    = (const float*)d_in[1];
    const float* bl    = (const float*)d_in[2];
    const float* Wc    = (const float*)d_in[3];
    const float* gamma = (const float*)d_in[4];
    const float* beta  = (const float*)d_in[5];
    const float* W2    = (const float*)d_in[6];
    const float* b2    = (const float*)d_in[7];
    const int* in_idx  = (const int*)d_in[8];
    const int* out_idx = (const int*)d_in[9];

    const int n = in_sizes[0] / 256;        // 200000
    const int M = in_sizes[8] / (4 * 27);   // max pairs per (p,k)

    float* accum = (float*)d_out;           // conv accumulator = d_out

    // workspace: hb[(n+1)*256] bf16 (row n = zero sentinel), WcT bf16, stats
    __hip_bfloat16* hb = (__hip_bfloat16*)d_ws;
    const size_t hb_bytes = (size_t)(n + 1) * 256 * sizeof(__hip_bfloat16);
    __hip_bfloat16* wct = (__hip_bfloat16*)((char*)d_ws + hb_bytes);
    const size_t wct_bytes = (size_t)4 * 27 * 4096 * sizeof(__hip_bfloat16);
    float* stats = (float*)((char*)d_ws + hb_bytes + wct_bytes);
    float* ssum = stats, *ssq = stats + 256;
    float* scalev = stats + 512, *shiftv = stats + 768;

    hipMemsetAsync(stats, 0, 512 * sizeof(float), stream);
    hipMemsetAsync(hb + (size_t)n * 256, 0, 256 * sizeof(__hip_bfloat16), stream);

    k0_wct<<<dim3(108), 256, 0, stream>>>(Wc, wct);

    const int rb  = n / 64;           // 3125
    const int rb2 = (n + 127) >> 7;   // 1563

    dim3 g1(rb, 4);
    k1_gemm_h<<<g1, 256, 0, stream>>>(x, Wl, bl, hb, n);

    dim3 g2(rb2, 4);
    k2_conv<<<g2, 512, 0, stream>>>(hb, wct, in_idx, out_idx, accum, n, M);

    k3_stats<<<512, 256, 0, stream>>>(accum, ssum, ssq, n);
    k3_final<<<1, 256, 0, stream>>>(ssum, ssq, gamma, beta, scalev, shiftv, n);

    k4_gemm_out<<<rb, 256, 0, stream>>>(accum, W2, b2, x, scalev, shiftv, n);
}

// Round 3
// 1134.833 us; speedup vs baseline: 2.0322x; 1.4764x over previous
//
#include <hip/hip_runtime.h>
#include <hip/hip_bf16.h>

constexpr float EPS = 1e-5f;

typedef _Float16 f16x8 __attribute__((ext_vector_type(8)));  // 8 fp16 = 4 VGPRs
typedef __attribute__((ext_vector_type(4))) float floatx4;   // MFMA C/D

// ---------------------------------------------------------------------------
// K0a: Wc[p][k][cin][d] fp32 -> wct[p][k][d][cin] fp16, 16B-chunk-swizzled
// (stored chunk sc of row d holds logical chunk sc^(d&7)) so k2 stages it
// with a LINEAR global_load_lds and reads B fragments conflict-free.
// ---------------------------------------------------------------------------
__global__ __launch_bounds__(256) void k0_wct(
    const float* __restrict__ Wc, _Float16* __restrict__ wct)
{
    __shared__ float T[64][65];
    const int pk = blockIdx.x;                   // p*27+k
    const float* src = Wc + (size_t)pk * 4096;   // [cin][d] fp32
    _Float16* dst = wct + (size_t)pk * 4096;
    const int t = threadIdx.x;
    #pragma unroll
    for (int e = 0; e < 16; e++) {
        const int idx = t + 256 * e;             // cin = idx>>6, d = idx&63
        T[idx >> 6][idx & 63] = src[idx];
    }
    __syncthreads();
    #pragma unroll
    for (int e = 0; e < 16; e++) {
        const int idx = t + 256 * e;             // out: row d, stored pos q
        const int d = idx >> 6, q = idx & 63;
        const int sc = q >> 3, j = q & 7;
        const int cin = ((sc ^ (d & 7)) << 3) | j;
        dst[idx] = (_Float16)T[cin][d];
    }
}

// ---------------------------------------------------------------------------
// K0b: Wl[p][c][d] fp32 -> wlt[p*64+d][c] fp16 (plain transpose; the LDS
// chunk swizzle is applied by k1's per-lane stage addressing).
// ---------------------------------------------------------------------------
__global__ __launch_bounds__(256) void k0_wlt(
    const float* __restrict__ Wl, _Float16* __restrict__ wlt)
{
    __shared__ float T[64][65];
    const int p = blockIdx.x, ct = blockIdx.y;
    const int t = threadIdx.x;
    #pragma unroll
    for (int e = 0; e < 16; e++) {
        const int idx = t + 256 * e;             // c' = idx>>6, d = idx&63
        const int c = idx >> 6, d = idx & 63;
        T[c][d] = Wl[((size_t)p * 256 + ct * 64 + c) * 64 + d];
    }
    __syncthreads();
    #pragma unroll
    for (int e = 0; e < 16; e++) {
        const int idx = t + 256 * e;             // d = idx>>6, c' = idx&63
        const int d = idx >> 6, c = idx & 63;
        wlt[((size_t)p * 64 + d) * 256 + ct * 64 + c] = (_Float16)T[c][d];
    }
}

// ---------------------------------------------------------------------------
// K0c: W2[k][c] fp32 -> w2t[c][k] fp16 (plain transpose).
// ---------------------------------------------------------------------------
__global__ __launch_bounds__(256) void k0_w2t(
    const float* __restrict__ W2, _Float16* __restrict__ w2t)
{
    __shared__ float T[64][65];
    const int kt = blockIdx.x, ct = blockIdx.y;
    const int t = threadIdx.x;
    #pragma unroll
    for (int e = 0; e < 16; e++) {
        const int idx = t + 256 * e;             // k' = idx>>6, c' = idx&63
        const int kk = idx >> 6, c = idx & 63;
        T[kk][c] = W2[((size_t)kt * 64 + kk) * 256 + ct * 64 + c];
    }
    __syncthreads();
    #pragma unroll
    for (int e = 0; e < 16; e++) {
        const int idx = t + 256 * e;             // c' = idx>>6, k' = idx&63
        const int c = idx >> 6, kk = idx & 63;
        w2t[((size_t)ct * 64 + c) * 256 + kt * 64 + kk] = (_Float16)T[kk][c];
    }
}

// ---------------------------------------------------------------------------
// K1: hb[n,256] fp16 = x[n,256] @ WlT (+ bl). fp16 MFMA GEMM, 128 rows/block,
// 512 thr. A: fp32->fp16 cvt during LDS staging (chunk-XOR swizzled). B tile
// [64 cols][128 k] staged per (kh,cg) by linear global_load_lds with the
// swizzle folded into the per-lane SOURCE address. acc[4 cg][4 tc] in regs.
// ---------------------------------------------------------------------------
__global__ __launch_bounds__(512, 4) void k1_gemm_h(
    const float* __restrict__ x, const _Float16* __restrict__ wlt,
    const float* __restrict__ bl, _Float16* __restrict__ hb, int n)
{
    __shared__ __align__(16) _Float16 As[128 * 128];  // 32 KB
    __shared__ __align__(16) _Float16 Bs[64 * 128];   // 16 KB
    __shared__ float blS[256];

    const int row0 = blockIdx.x << 7;
    const int t    = threadIdx.x;
    const int lane = t & 63;
    const int wv   = t >> 6;
    const int mrow = lane & 15;
    const int quad = lane >> 4;

    if (t < 256) blS[t] = bl[t];

    floatx4 acc[4][4];
    #pragma unroll
    for (int a = 0; a < 4; a++)
        #pragma unroll
        for (int b = 0; b < 4; b++) acc[a][b] = floatx4{0.f, 0.f, 0.f, 0.f};

    #pragma unroll
    for (int kh = 0; kh < 2; kh++) {
        __syncthreads();  // previous compute's As/Bs reads done
        // stage A half-tile: rows 0..127, k = kh*128..+127
        #pragma unroll
        for (int i = 0; i < 4; i++) {
            const int cid = t + 512 * i;          // 2048 chunks
            const int r = cid >> 4, ck = cid & 15;
            const int gr = row0 + r;
            f16x8 v;
            if (gr < n) {
                const float* g = x + (size_t)gr * 256 + kh * 128 + (ck << 3);
                const float4 f0 = *(const float4*)g;
                const float4 f1 = *(const float4*)(g + 4);
                v[0] = (_Float16)f0.x; v[1] = (_Float16)f0.y;
                v[2] = (_Float16)f0.z; v[3] = (_Float16)f0.w;
                v[4] = (_Float16)f1.x; v[5] = (_Float16)f1.y;
                v[6] = (_Float16)f1.z; v[7] = (_Float16)f1.w;
            } else {
                #pragma unroll
                for (int j = 0; j < 8; j++) v[j] = (_Float16)0.f;
            }
            *(f16x8*)&As[r * 128 + ((ck ^ (r & 7)) << 3)] = v;
        }
        #pragma unroll
        for (int cg = 0; cg < 4; cg++) {
            __syncthreads();  // A staged / prev Bs reads done
            #pragma unroll
            for (int it = 0; it < 2; it++) {
                const int lin = t + 512 * it;     // 1024 chunks
                const int r = lin >> 4, sc = lin & 15;
                const _Float16* gs = wlt + (size_t)(cg * 64 + r) * 256
                                     + kh * 128 + ((sc ^ (r & 7)) << 3);
                __builtin_amdgcn_global_load_lds(
                    (const __attribute__((address_space(1))) void*)gs,
                    (__attribute__((address_space(3))) void*)((char*)Bs + lin * 16),
                    16, 0, 0);
            }
            __syncthreads();  // drains vmcnt: B staged
            #pragma unroll
            for (int s = 0; s < 4; s++) {
                const int r = (wv << 4) + mrow;
                const f16x8 a = *(const f16x8*)&As[r * 128 + ((((s << 2) + quad) ^ (r & 7)) << 3)];
                #pragma unroll
                for (int tc = 0; tc < 4; tc++) {
                    const int rn = (tc << 4) + mrow;
                    const f16x8 b = *(const f16x8*)&Bs[rn * 128 + ((((s << 2) + quad) ^ (rn & 7)) << 3)];
                    acc[cg][tc] = __builtin_amdgcn_mfma_f32_16x16x32_f16(a, b, acc[cg][tc], 0, 0, 0);
                }
            }
        }
    }
    __syncthreads();
    #pragma unroll
    for (int cg = 0; cg < 4; cg++)
        #pragma unroll
        for (int tc = 0; tc < 4; tc++)
            #pragma unroll
            for (int rg = 0; rg < 4; rg++) {
                const int r = row0 + (wv << 4) + (quad << 2) + rg;
                const int c = (cg << 6) + (tc << 4) + mrow;
                if (r < n)
                    hb[(size_t)r * 256 + c] = (_Float16)(acc[cg][tc][rg] + blS[c]);
            }
}

// ---------------------------------------------------------------------------
// K2: gather conv (fp16), unchanged structure from r2 + fused BN stats:
// after the k-loop the 128x64 patch lives in LDS Acc -> per-column partial
// sum/sumsq reduced in LDS (reusing Ws) and atomicAdd'ed once per column.
// ---------------------------------------------------------------------------
__global__ __launch_bounds__(512) void k2_conv(
    const _Float16* __restrict__ hb, const _Float16* __restrict__ wct,
    const int* __restrict__ in_idx, const int* __restrict__ out_idx,
    float* __restrict__ accum, float* __restrict__ ssum,
    float* __restrict__ ssq, int n, int M)
{
    __shared__ __align__(16) _Float16 Ws[2][4096];  // [d][64] swizzled chunks
    __shared__ float Acc[128][66];
    __shared__ int csrc[2][128];
    __shared__ int cdst[2][128];
    __shared__ int spos_s[27];
    __shared__ int epos_s[27];

    const int p    = blockIdx.y;
    const int t    = threadIdx.x;
    const int lane = t & 63;
    const int wv   = t >> 6;
    const int mrow = lane & 15;
    const int quad = lane >> 4;

    // bijective XCD-chunked swizzle of the row-block index
    const int nwg = gridDim.x;
    const int qq = nwg >> 3, rr = nwg & 7;
    const int xcd = blockIdx.x & 7, ii = blockIdx.x >> 3;
    const int bx = (xcd < rr ? xcd * (qq + 1) : rr * (qq + 1) + (xcd - rr) * qq) + ii;
    const int row0 = bx << 7;

    for (int i = t; i < 128 * 66; i += 512) ((float*)Acc)[i] = 0.0f;

    if (t < 54) {
        const int kk = (t < 27) ? t : t - 27;
        const int upper = (row0 + 128 > n) ? n : row0 + 128;  // exclude sentinels (==n)
        const int target = (t < 27) ? row0 : upper;
        const int* oi = out_idx + (size_t)(p * 27 + kk) * M;
        int lo = 0, hi = M;
        while (lo < hi) {
            const int mid = (lo + hi) >> 1;
            if (oi[mid] < target) lo = mid + 1; else hi = mid;
        }
        if (t < 27) spos_s[kk] = lo; else epos_s[kk] = lo;
    }
    __syncthreads();

#define STAGE(buf, kk) do {                                                         \
        const char* gs_ = (const char*)wct + (((size_t)(p * 27 + (kk))) << 13)      \
                          + (wv << 10) + (lane << 4);                               \
        __builtin_amdgcn_global_load_lds(                                           \
            (const __attribute__((address_space(1))) void*)gs_,                     \
            (__attribute__((address_space(3))) void*)((char*)&Ws[buf][0] + (wv << 10)), \
            16, 0, 0);                                                              \
    } while (0)

#define COMPACT(buf, kk) do {                                                       \
        if (t < 128) {                                                              \
            const int sp_ = spos_s[kk];                                             \
            int cn_ = epos_s[kk] - sp_;                                             \
            if (cn_ > 128) cn_ = 128;                                               \
            const size_t base_ = (size_t)(p * 27 + (kk)) * M + sp_;                 \
            int v_ = n;                                                             \
            if (t < cn_) {                                                          \
                v_ = in_idx[base_ + t];                                             \
                cdst[buf][t] = out_idx[base_ + t] - row0;                           \
            }                                                                       \
            csrc[buf][t] = v_;                                                      \
        }                                                                           \
    } while (0)

    STAGE(0, 0);
    COMPACT(0, 0);
    __syncthreads();

    for (int k = 0; k < 27; k++) {
        const int cur = k & 1;
        if (k < 26) { STAGE(cur ^ 1, k + 1); COMPACT(cur ^ 1, k + 1); }

        int cnt = epos_s[k] - spos_s[k];
        if (cnt > 128) cnt = 128;
        const int tids = ((cnt + 15) >> 4) << 2;   // TR*4
        const int bsw  = (quad ^ (mrow & 7)) << 3;

        for (int tid = wv; tid < tids; tid += 8) {
            const int tr = tid >> 2, tc = tid & 3;
            const int srow = csrc[cur][(tr << 4) + mrow];
            const _Float16* ar = hb + ((size_t)srow << 8) + (p << 6) + (quad << 3);
            const f16x8 a0 = *(const f16x8*)ar;
            const f16x8 a1 = *(const f16x8*)(ar + 32);
            const int brow = ((tc << 4) + mrow) << 6;
            const f16x8 b0 = *(const f16x8*)(Ws[cur] + brow + bsw);
            const f16x8 b1 = *(const f16x8*)(Ws[cur] + brow + (bsw ^ 32));
            floatx4 c = {0.f, 0.f, 0.f, 0.f};
            c = __builtin_amdgcn_mfma_f32_16x16x32_f16(a0, b0, c, 0, 0, 0);
            c = __builtin_amdgcn_mfma_f32_16x16x32_f16(a1, b1, c, 0, 0, 0);
            #pragma unroll
            for (int rg = 0; rg < 4; rg++) {
                const int m = (tr << 4) + (quad << 2) + rg;
                if (m < cnt)
                    Acc[cdst[cur][m]][(tc << 4) + mrow] += c[rg];
            }
        }
        __syncthreads();
    }

    // ---- fused BN stats: per-column sum/sumsq of the patch (rows>=n are 0)
    {
        const int col = t & 63;
        float s = 0.f, s2 = 0.f;
        for (int r = wv; r < 128; r += 8) {
            const float v = Acc[r][col];
            s += v; s2 += v * v;
        }
        float* red = (float*)&Ws[0][0];   // 16 KB scratch, staging all drained
        red[wv * 64 + col] = s;
        red[512 + wv * 64 + col] = s2;
        __syncthreads();
        if (t < 64) {
            float a = 0.f, b = 0.f;
            #pragma unroll
            for (int w = 0; w < 8; w++) {
                a += red[w * 64 + t];
                b += red[512 + w * 64 + t];
            }
            atomicAdd(&ssum[(p << 6) + t], a);
            atomicAdd(&ssq[(p << 6) + t], b);
        }
    }

    // streaming write of the block's 128x64 patch
    for (int i = t; i < 128 * 32; i += 512) {
        const int r = i >> 5, cc = (i & 31) << 1;
        const int gr = row0 + r;
        if (gr < n)
            *(float2*)(accum + (size_t)gr * 256 + (p << 6) + cc) =
                *(const float2*)&Acc[r][cc];
    }
#undef STAGE
#undef COMPACT
}

// ---------------------------------------------------------------------------
__global__ void k3_final(
    const float* __restrict__ ssum, const float* __restrict__ ssq,
    const float* __restrict__ gamma, const float* __restrict__ beta,
    float* __restrict__ scale, float* __restrict__ shift, int n)
{
    const int t = threadIdx.x;  // 256
    const float inv_n = 1.0f / (float)n;
    const float mu  = ssum[t] * inv_n;
    const float var = ssq[t] * inv_n - mu * mu;
    const float sc  = gamma[t] * rsqrtf(var + EPS);
    scale[t] = sc;
    shift[t] = beta[t] - mu * sc;
}

// ---------------------------------------------------------------------------
// K4: io[n,256] = relu(io*scale+shift) @ W2 + b2 + x, IN-PLACE on d_out.
// Same fp16 MFMA structure as k1; A = BN+ReLU applied during staging.
// ---------------------------------------------------------------------------
__global__ __launch_bounds__(512, 4) void k4_gemm_out(
    float* __restrict__ io, const _Float16* __restrict__ w2t,
    const float* __restrict__ b2, const float* __restrict__ x,
    const float* __restrict__ scale, const float* __restrict__ shift, int n)
{
    __shared__ __align__(16) _Float16 As[128 * 128];
    __shared__ __align__(16) _Float16 Bs[64 * 128];
    __shared__ float scS[256], shS[256], b2S[256];

    const int row0 = blockIdx.x << 7;
    const int t    = threadIdx.x;
    const int lane = t & 63;
    const int wv   = t >> 6;
    const int mrow = lane & 15;
    const int quad = lane >> 4;

    if (t < 256) { scS[t] = scale[t]; shS[t] = shift[t]; b2S[t] = b2[t]; }

    floatx4 acc[4][4];
    #pragma unroll
    for (int a = 0; a < 4; a++)
        #pragma unroll
        for (int b = 0; b < 4; b++) acc[a][b] = floatx4{0.f, 0.f, 0.f, 0.f};

    #pragma unroll
    for (int kh = 0; kh < 2; kh++) {
        __syncthreads();  // scS ready (kh=0) / prev As reads done
        #pragma unroll
        for (int i = 0; i < 4; i++) {
            const int cid = t + 512 * i;
            const int r = cid >> 4, ck = cid & 15;
            const int gr = row0 + r;
            const int kg = kh * 128 + (ck << 3);
            f16x8 v;
            if (gr < n) {
                const float* g = io + (size_t)gr * 256 + kg;
                const float4 f0 = *(const float4*)g;
                const float4 f1 = *(const float4*)(g + 4);
                float f[8] = {f0.x, f0.y, f0.z, f0.w, f1.x, f1.y, f1.z, f1.w};
                #pragma unroll
                for (int j = 0; j < 8; j++)
                    v[j] = (_Float16)fmaxf(f[j] * scS[kg + j] + shS[kg + j], 0.f);
            } else {
                #pragma unroll
                for (int j = 0; j < 8; j++) v[j] = (_Float16)0.f;
            }
            *(f16x8*)&As[r * 128 + ((ck ^ (r & 7)) << 3)] = v;
        }
        #pragma unroll
        for (int cg = 0; cg < 4; cg++) {
            __syncthreads();
            #pragma unroll
            for (int it = 0; it < 2; it++) {
                const int lin = t + 512 * it;
                const int r = lin >> 4, sc = lin & 15;
                const _Float16* gs = w2t + (size_t)(cg * 64 + r) * 256
                                     + kh * 128 + ((sc ^ (r & 7)) << 3);
                __builtin_amdgcn_global_load_lds(
                    (const __attribute__((address_space(1))) void*)gs,
                    (__attribute__((address_space(3))) void*)((char*)Bs + lin * 16),
                    16, 0, 0);
            }
            __syncthreads();
            #pragma unroll
            for (int s = 0; s < 4; s++) {
                const int r = (wv << 4) + mrow;
                const f16x8 a = *(const f16x8*)&As[r * 128 + ((((s << 2) + quad) ^ (r & 7)) << 3)];
                #pragma unroll
                for (int tc = 0; tc < 4; tc++) {
                    const int rn = (tc << 4) + mrow;
                    const f16x8 b = *(const f16x8*)&Bs[rn * 128 + ((((s << 2) + quad) ^ (rn & 7)) << 3)];
                    acc[cg][tc] = __builtin_amdgcn_mfma_f32_16x16x32_f16(a, b, acc[cg][tc], 0, 0, 0);
                }
            }
        }
    }
    __syncthreads();  // all io reads done before in-place writes
    #pragma unroll
    for (int cg = 0; cg < 4; cg++)
        #pragma unroll
        for (int tc = 0; tc < 4; tc++)
            #pragma unroll
            for (int rg = 0; rg < 4; rg++) {
                const int r = row0 + (wv << 4) + (quad << 2) + rg;
                const int c = (cg << 6) + (tc << 4) + mrow;
                if (r < n)
                    io[(size_t)r * 256 + c] = acc[cg][tc][rg] + b2S[c] + x[(size_t)r * 256 + c];
            }
}

// ---------------------------------------------------------------------------
extern "C" void kernel_launch(void* const* d_in, const int* in_sizes, int n_in,
                              void* d_out, int out_size, void* d_ws, size_t ws_size,
                              hipStream_t stream)
{
    const float* x     = (const float*)d_in[0];
    const float* Wl    = (const float*)d_in[1];
    const float* bl    = (const float*)d_in[2];
    const float* Wc    = (const float*)d_in[3];
    const float* gamma = (const float*)d_in[4];
    const float* beta  = (const float*)d_in[5];
    const float* W2    = (const float*)d_in[6];
    const float* b2    = (const float*)d_in[7];
    const int* in_idx  = (const int*)d_in[8];
    const int* out_idx = (const int*)d_in[9];

    const int n = in_sizes[0] / 256;        // 200000
    const int M = in_sizes[8] / (4 * 27);   // max pairs per (p,k)

    float* accum = (float*)d_out;

    // workspace: hb[(n+1)*256] fp16 (row n = zero sentinel), wct, wlt, w2t, stats
    _Float16* hb = (_Float16*)d_ws;
    const size_t hb_bytes = (size_t)(n + 1) * 256 * sizeof(_Float16);
    _Float16* wct = (_Float16*)((char*)d_ws + hb_bytes);
    const size_t wct_bytes = (size_t)4 * 27 * 4096 * sizeof(_Float16);
    _Float16* wlt = (_Float16*)((char*)wct + wct_bytes);
    _Float16* w2t = (_Float16*)((char*)wlt + 256 * 256 * sizeof(_Float16));
    float* stats = (float*)((char*)w2t + 256 * 256 * sizeof(_Float16));
    float* ssum = stats, *ssq = stats + 256;
    float* scalev = stats + 512, *shiftv = stats + 768;

    hipMemsetAsync(stats, 0, 512 * sizeof(float), stream);
    hipMemsetAsync(hb + (size_t)n * 256, 0, 256 * sizeof(_Float16), stream);

    k0_wct<<<dim3(108), 256, 0, stream>>>(Wc, wct);
    k0_wlt<<<dim3(4, 4), 256, 0, stream>>>(Wl, wlt);
    k0_w2t<<<dim3(4, 4), 256, 0, stream>>>(W2, w2t);

    const int rb2 = (n + 127) >> 7;   // 1563

    k1_gemm_h<<<rb2, 512, 0, stream>>>(x, wlt, bl, hb, n);

    dim3 g2(rb2, 4);
    k2_conv<<<g2, 512, 0, stream>>>(hb, wct, in_idx, out_idx, accum, ssum, ssq, n, M);

    k3_final<<<1, 256, 0, stream>>>(ssum, ssq, gamma, beta, scalev, shiftv, n);

    k4_gemm_out<<<rb2, 512, 0, stream>>>(accum, w2t, b2, x, scalev, shiftv, n);
}

// Round 4
// 1001.618 us; speedup vs baseline: 2.3025x; 1.1330x over previous
//
#include <hip/hip_runtime.h>
#include <hip/hip_bf16.h>

constexpr float EPS = 1e-5f;

typedef _Float16 f16x8 __attribute__((ext_vector_type(8)));  // 8 fp16 = 4 VGPRs
typedef __attribute__((ext_vector_type(4))) float floatx4;   // MFMA C/D

// ---------------------------------------------------------------------------
// K0a: Wc[p][k][cin][d] fp32 -> wct[p][k][d][cin] fp16, 16B-chunk-swizzled
// (stored chunk sc of row d holds logical chunk sc^(d&7)) so k2 stages it
// with a LINEAR global_load_lds and reads B fragments conflict-free.
// ---------------------------------------------------------------------------
__global__ __launch_bounds__(256) void k0_wct(
    const float* __restrict__ Wc, _Float16* __restrict__ wct)
{
    __shared__ float T[64][65];
    const int pk = blockIdx.x;                   // p*27+k
    const float* src = Wc + (size_t)pk * 4096;   // [cin][d] fp32
    _Float16* dst = wct + (size_t)pk * 4096;
    const int t = threadIdx.x;
    #pragma unroll
    for (int e = 0; e < 16; e++) {
        const int idx = t + 256 * e;             // cin = idx>>6, d = idx&63
        T[idx >> 6][idx & 63] = src[idx];
    }
    __syncthreads();
    #pragma unroll
    for (int e = 0; e < 16; e++) {
        const int idx = t + 256 * e;             // out: row d, stored pos q
        const int d = idx >> 6, q = idx & 63;
        const int sc = q >> 3, j = q & 7;
        const int cin = ((sc ^ (d & 7)) << 3) | j;
        dst[idx] = (_Float16)T[cin][d];
    }
}

// ---------------------------------------------------------------------------
// K0b: Wl[p][c][d] fp32 -> wlt[p*64+d][c] fp16 (plain transpose).
// ---------------------------------------------------------------------------
__global__ __launch_bounds__(256) void k0_wlt(
    const float* __restrict__ Wl, _Float16* __restrict__ wlt)
{
    __shared__ float T[64][65];
    const int p = blockIdx.x, ct = blockIdx.y;
    const int t = threadIdx.x;
    #pragma unroll
    for (int e = 0; e < 16; e++) {
        const int idx = t + 256 * e;
        const int c = idx >> 6, d = idx & 63;
        T[c][d] = Wl[((size_t)p * 256 + ct * 64 + c) * 64 + d];
    }
    __syncthreads();
    #pragma unroll
    for (int e = 0; e < 16; e++) {
        const int idx = t + 256 * e;
        const int d = idx >> 6, c = idx & 63;
        wlt[((size_t)p * 64 + d) * 256 + ct * 64 + c] = (_Float16)T[c][d];
    }
}

// ---------------------------------------------------------------------------
// K0c: W2[k][c] fp32 -> w2t[c][k] fp16 (plain transpose).
// ---------------------------------------------------------------------------
__global__ __launch_bounds__(256) void k0_w2t(
    const float* __restrict__ W2, _Float16* __restrict__ w2t)
{
    __shared__ float T[64][65];
    const int kt = blockIdx.x, ct = blockIdx.y;
    const int t = threadIdx.x;
    #pragma unroll
    for (int e = 0; e < 16; e++) {
        const int idx = t + 256 * e;
        const int kk = idx >> 6, c = idx & 63;
        T[kk][c] = W2[((size_t)kt * 64 + kk) * 256 + ct * 64 + c];
    }
    __syncthreads();
    #pragma unroll
    for (int e = 0; e < 16; e++) {
        const int idx = t + 256 * e;
        const int c = idx >> 6, kk = idx & 63;
        w2t[((size_t)ct * 64 + c) * 256 + kt * 64 + kk] = (_Float16)T[kk][c];
    }
}

// ---------------------------------------------------------------------------
// K1: hb[n,256] fp16 = x[n,256] @ WlT (+ bl). fp16 MFMA, 128 rows/block.
// B is DOUBLE-BUFFERED: B(st+1) issued right after the st-head barrier so
// its L2 latency hides under compute(st) instead of being drained serially.
// ---------------------------------------------------------------------------
__global__ __launch_bounds__(512, 4) void k1_gemm_h(
    const float* __restrict__ x, const _Float16* __restrict__ wlt,
    const float* __restrict__ bl, _Float16* __restrict__ hb, int n)
{
    __shared__ __align__(16) _Float16 As[128 * 128];     // 32 KB
    __shared__ __align__(16) _Float16 Bs[2][64 * 128];   // 2x16 KB
    __shared__ float blS[256];

    const int row0 = blockIdx.x << 7;
    const int t    = threadIdx.x;
    const int lane = t & 63;
    const int wv   = t >> 6;
    const int mrow = lane & 15;
    const int quad = lane >> 4;

#define STAGE_B1(buf_, st_) do {                                                \
        const int kh_ = (st_) >> 2, cg_ = (st_) & 3;                            \
        _Pragma("unroll")                                                       \
        for (int it = 0; it < 2; it++) {                                        \
            const int lin = t + 512 * it;                                       \
            const int r = lin >> 4, sc = lin & 15;                              \
            const _Float16* gs = wlt + (size_t)(cg_ * 64 + r) * 256             \
                                 + kh_ * 128 + ((sc ^ (r & 7)) << 3);           \
            __builtin_amdgcn_global_load_lds(                                   \
                (const __attribute__((address_space(1))) void*)gs,              \
                (__attribute__((address_space(3))) void*)                       \
                    ((char*)&Bs[buf_][0] + lin * 16),                           \
                16, 0, 0);                                                      \
        }                                                                       \
    } while (0)

    if (t < 256) blS[t] = bl[t];
    STAGE_B1(0, 0);   // prologue: B(0) in flight

    floatx4 acc[4][4];
    #pragma unroll
    for (int a = 0; a < 4; a++)
        #pragma unroll
        for (int b = 0; b < 4; b++) acc[a][b] = floatx4{0.f, 0.f, 0.f, 0.f};

    #pragma unroll
    for (int kh = 0; kh < 2; kh++) {
        __syncthreads();  // kh=1: previous As reads done before overwrite
        // stage A half-tile: rows 0..127, k = kh*128..+127 (fp32->fp16 cvt)
        #pragma unroll
        for (int i = 0; i < 4; i++) {
            const int cid = t + 512 * i;          // 2048 chunks
            const int r = cid >> 4, ck = cid & 15;
            const int gr = row0 + r;
            f16x8 v;
            if (gr < n) {
                const float* g = x + (size_t)gr * 256 + kh * 128 + (ck << 3);
                const float4 f0 = *(const float4*)g;
                const float4 f1 = *(const float4*)(g + 4);
                v[0] = (_Float16)f0.x; v[1] = (_Float16)f0.y;
                v[2] = (_Float16)f0.z; v[3] = (_Float16)f0.w;
                v[4] = (_Float16)f1.x; v[5] = (_Float16)f1.y;
                v[6] = (_Float16)f1.z; v[7] = (_Float16)f1.w;
            } else {
                #pragma unroll
                for (int j = 0; j < 8; j++) v[j] = (_Float16)0.f;
            }
            *(f16x8*)&As[r * 128 + ((ck ^ (r & 7)) << 3)] = v;
        }
        #pragma unroll
        for (int cg = 0; cg < 4; cg++) {
            const int st = kh * 4 + cg;
            __syncthreads();  // drains vmcnt: B(st) ready; A visible (cg=0)
            if (st < 7) {
                if (st == 0) STAGE_B1(1, 1);
                else if (st == 1) STAGE_B1(0, 2);
                else if (st == 2) STAGE_B1(1, 3);
                else if (st == 3) STAGE_B1(0, 4);
                else if (st == 4) STAGE_B1(1, 5);
                else if (st == 5) STAGE_B1(0, 6);
                else              STAGE_B1(1, 7);
            }
            #pragma unroll
            for (int s = 0; s < 4; s++) {
                const int r = (wv << 4) + mrow;
                const f16x8 a = *(const f16x8*)&As[r * 128 + ((((s << 2) + quad) ^ (r & 7)) << 3)];
                #pragma unroll
                for (int tc = 0; tc < 4; tc++) {
                    const int rn = (tc << 4) + mrow;
                    const f16x8 b = *(const f16x8*)&Bs[st & 1][rn * 128 + ((((s << 2) + quad) ^ (rn & 7)) << 3)];
                    acc[cg][tc] = __builtin_amdgcn_mfma_f32_16x16x32_f16(a, b, acc[cg][tc], 0, 0, 0);
                }
            }
        }
    }
    #pragma unroll
    for (int cg = 0; cg < 4; cg++)
        #pragma unroll
        for (int tc = 0; tc < 4; tc++)
            #pragma unroll
            for (int rg = 0; rg < 4; rg++) {
                const int r = row0 + (wv << 4) + (quad << 2) + rg;
                const int c = (cg << 6) + (tc << 4) + mrow;
                if (r < n)
                    hb[(size_t)r * 256 + c] = (_Float16)(acc[cg][tc][rg] + blS[c]);
            }
#undef STAGE_B1
}

// ---------------------------------------------------------------------------
// K2: gather conv, REGISTER-RESIDENT output. Per k, the inverse map
// src2[out_row-row0] = (k<<19)|in_row is scattered (tagged: stale entries
// self-invalidate -> no zero-init, ONE barrier per k). Each wave owns 16
// fixed out rows; A frags gathered per-lane from global hb via src2
// (sentinel n = zero row); acc[4] stays in VGPRs across all 27 k. Gathers /
// idx-prefetch / W-stage for k+1..k+3 issue early each phase (latency hides
// under compute before the barrier drain). BN stats reduced from regs.
// ---------------------------------------------------------------------------
__global__ __launch_bounds__(512, 4) void k2_conv(
    const _Float16* __restrict__ hb, const _Float16* __restrict__ wct,
    const int* __restrict__ in_idx, const int* __restrict__ out_idx,
    float* __restrict__ accum, float* __restrict__ ssum,
    float* __restrict__ ssq, int n, int M)
{
    __shared__ __align__(16) _Float16 Ws[2][4096];  // [d][64] swizzled chunks
    __shared__ int src2[4][128];                    // tagged inverse maps
    __shared__ int spos_s[27];
    __shared__ int epos_s[27];
    __shared__ float redS[8][64];
    __shared__ float redQ[8][64];

    const int p    = blockIdx.y;
    const int t    = threadIdx.x;
    const int lane = t & 63;
    const int wv   = t >> 6;
    const int mrow = lane & 15;
    const int quad = lane >> 4;

    // bijective XCD-chunked swizzle of the row-block index
    const int nwg = gridDim.x;
    const int qq = nwg >> 3, rr = nwg & 7;
    const int xcd = blockIdx.x & 7, ii = blockIdx.x >> 3;
    const int bx = (xcd < rr ? xcd * (qq + 1) : rr * (qq + 1) + (xcd - rr) * qq) + ii;
    const int row0 = bx << 7;

    const int SENT = 31 << 19;   // tag never produced by any k (k<=28)

    if (t < 54) {
        const int kk = (t < 27) ? t : t - 27;
        const int upper = (row0 + 128 > n) ? n : row0 + 128;  // exclude sentinels
        const int target = (t < 27) ? row0 : upper;
        const int* oi = out_idx + (size_t)(p * 27 + kk) * M;
        int lo = 0, hi = M;
        while (lo < hi) {
            const int mid = (lo + hi) >> 1;
            if (oi[mid] < target) lo = mid + 1; else hi = mid;
        }
        if (t < 27) spos_s[kk] = lo; else epos_s[kk] = lo;
    }
    if (t < 128) {
        src2[0][t] = SENT; src2[1][t] = SENT;
        src2[2][t] = SENT; src2[3][t] = SENT;
    }
    __syncthreads();

#define STAGE(buf, kk) do {                                                         \
        const char* gs_ = (const char*)wct + (((size_t)(p * 27 + (kk))) << 13)      \
                          + (t << 4);                                               \
        __builtin_amdgcn_global_load_lds(                                           \
            (const __attribute__((address_space(1))) void*)gs_,                     \
            (__attribute__((address_space(3))) void*)((char*)&Ws[buf][0] + (t << 4)), \
            16, 0, 0);                                                              \
    } while (0)

    // prologue: scatter K=0,1 inline; prefetch idx for K=2; stage Ws[0]
    int ivS = 0, ovS = 0, cntS = 0;
    if (t < 128) {
        #pragma unroll
        for (int K = 0; K < 2; K++) {
            int c = epos_s[K] - spos_s[K];
            if (c > 128) c = 128;
            if (t < c) {
                const size_t b = (size_t)(p * 27 + K) * M + spos_s[K] + t;
                src2[K][out_idx[b] - row0] = (K << 19) | in_idx[b];
            }
        }
        cntS = epos_s[2] - spos_s[2];
        if (cntS > 128) cntS = 128;
        if (t < cntS) {
            const size_t b = (size_t)(p * 27 + 2) * M + spos_s[2] + t;
            ivS = in_idx[b]; ovS = out_idx[b];
        }
    }
    STAGE(0, 0);
    __syncthreads();   // scatters 0,1 visible; Ws[0] ready

    const int arow = (wv << 4) + mrow;     // this lane's out row (local)
    const int bsw  = (quad ^ (mrow & 7)) << 3;

    // gather for k=0 into g0
    f16x8 g0a, g0b, g1a, g1b;
    {
        const int v = src2[0][arow];
        const int src = ((v >> 19) == 0) ? (v & 0x7FFFF) : n;
        const _Float16* ar = hb + ((size_t)src << 8) + (p << 6) + (quad << 3);
        g0a = *(const f16x8*)ar;
        g0b = *(const f16x8*)(ar + 32);
    }

    floatx4 acc[4];
    #pragma unroll
    for (int tc = 0; tc < 4; tc++) acc[tc] = floatx4{0.f, 0.f, 0.f, 0.f};

    for (int k = 0; k < 27; k++) {
        // 1. issue gather for k+1 (src2[(k+1)&3] scattered at iter k-1)
        if (k < 26) {
            const int v = src2[(k + 1) & 3][arow];
            const int src = ((v >> 19) == (k + 1)) ? (v & 0x7FFFF) : n;
            const _Float16* ar = hb + ((size_t)src << 8) + (p << 6) + (quad << 3);
            g1a = *(const f16x8*)ar;
            g1b = *(const f16x8*)(ar + 32);
        }
        // 2. scatter K=k+2 from prefetched regs
        if (k < 25 && t < cntS)
            src2[(k + 2) & 3][ovS - row0] = ((k + 2) << 19) | ivS;
        // 3. prefetch idx for K=k+3
        int ivN = 0, ovN = 0, cntN = 0;
        if (k < 24 && t < 128) {
            cntN = epos_s[k + 3] - spos_s[k + 3];
            if (cntN > 128) cntN = 128;
            if (t < cntN) {
                const size_t b = (size_t)(p * 27 + k + 3) * M + spos_s[k + 3] + t;
                ivN = in_idx[b]; ovN = out_idx[b];
            }
        }
        // 4. stage Ws for k+1
        if (k < 26) STAGE((k + 1) & 1, k + 1);
        // 5. compute k: 8 MFMA, acc stays in regs
        #pragma unroll
        for (int tc = 0; tc < 4; tc++) {
            const int brow = ((tc << 4) + mrow) << 6;
            const f16x8 b0 = *(const f16x8*)(Ws[k & 1] + brow + bsw);
            const f16x8 b1 = *(const f16x8*)(Ws[k & 1] + brow + (bsw ^ 32));
            acc[tc] = __builtin_amdgcn_mfma_f32_16x16x32_f16(g0a, b0, acc[tc], 0, 0, 0);
            acc[tc] = __builtin_amdgcn_mfma_f32_16x16x32_f16(g0b, b1, acc[tc], 0, 0, 0);
        }
        __syncthreads();  // scatters visible; Ws[k+1]/gathers drained
        g0a = g1a; g0b = g1b;
        ivS = ivN; ovS = ovN; cntS = cntN;
    }

    // ---- fused BN stats from registers (quad-shuffle reduce, then LDS)
    #pragma unroll
    for (int tc = 0; tc < 4; tc++) {
        float s = 0.f, q = 0.f;
        #pragma unroll
        for (int rg = 0; rg < 4; rg++) {
            const float v = acc[tc][rg];
            s += v; q += v * v;
        }
        s += __shfl_xor(s, 16); s += __shfl_xor(s, 32);
        q += __shfl_xor(q, 16); q += __shfl_xor(q, 32);
        if (quad == 0) {
            redS[wv][(tc << 4) + mrow] = s;
            redQ[wv][(tc << 4) + mrow] = q;
        }
    }
    __syncthreads();
    if (t < 64) {
        float a = 0.f, b = 0.f;
        #pragma unroll
        for (int w = 0; w < 8; w++) { a += redS[w][t]; b += redQ[w][t]; }
        atomicAdd(&ssum[(p << 6) + t], a);
        atomicAdd(&ssq[(p << 6) + t], b);
    }

    // ---- writeout straight from registers
    #pragma unroll
    for (int tc = 0; tc < 4; tc++)
        #pragma unroll
        for (int rg = 0; rg < 4; rg++) {
            const int r = row0 + (wv << 4) + (quad << 2) + rg;
            if (r < n)
                accum[(size_t)r * 256 + (p << 6) + (tc << 4) + mrow] = acc[tc][rg];
        }
#undef STAGE
}

// ---------------------------------------------------------------------------
__global__ void k3_final(
    const float* __restrict__ ssum, const float* __restrict__ ssq,
    const float* __restrict__ gamma, const float* __restrict__ beta,
    float* __restrict__ scale, float* __restrict__ shift, int n)
{
    const int t = threadIdx.x;  // 256
    const float inv_n = 1.0f / (float)n;
    const float mu  = ssum[t] * inv_n;
    const float var = ssq[t] * inv_n - mu * mu;
    const float sc  = gamma[t] * rsqrtf(var + EPS);
    scale[t] = sc;
    shift[t] = beta[t] - mu * sc;
}

// ---------------------------------------------------------------------------
// K4: io[n,256] = relu(io*scale+shift) @ W2 + b2 + x, IN-PLACE on d_out.
// Same double-buffered-B structure as k1; BN+ReLU applied during A staging.
// ---------------------------------------------------------------------------
__global__ __launch_bounds__(512, 4) void k4_gemm_out(
    float* __restrict__ io, const _Float16* __restrict__ w2t,
    const float* __restrict__ b2, const float* __restrict__ x,
    const float* __restrict__ scale, const float* __restrict__ shift, int n)
{
    __shared__ __align__(16) _Float16 As[128 * 128];
    __shared__ __align__(16) _Float16 Bs[2][64 * 128];
    __shared__ float scS[256], shS[256], b2S[256];

    const int row0 = blockIdx.x << 7;
    const int t    = threadIdx.x;
    const int lane = t & 63;
    const int wv   = t >> 6;
    const int mrow = lane & 15;
    const int quad = lane >> 4;

#define STAGE_B4(buf_, st_) do {                                                \
        const int kh_ = (st_) >> 2, cg_ = (st_) & 3;                            \
        _Pragma("unroll")                                                       \
        for (int it = 0; it < 2; it++) {                                        \
            const int lin = t + 512 * it;                                       \
            const int r = lin >> 4, sc = lin & 15;                              \
            const _Float16* gs = w2t + (size_t)(cg_ * 64 + r) * 256             \
                                 + kh_ * 128 + ((sc ^ (r & 7)) << 3);           \
            __builtin_amdgcn_global_load_lds(                                   \
                (const __attribute__((address_space(1))) void*)gs,              \
                (__attribute__((address_space(3))) void*)                       \
                    ((char*)&Bs[buf_][0] + lin * 16),                           \
                16, 0, 0);                                                      \
        }                                                                       \
    } while (0)

    if (t < 256) { scS[t] = scale[t]; shS[t] = shift[t]; b2S[t] = b2[t]; }
    STAGE_B4(0, 0);

    floatx4 acc[4][4];
    #pragma unroll
    for (int a = 0; a < 4; a++)
        #pragma unroll
        for (int b = 0; b < 4; b++) acc[a][b] = floatx4{0.f, 0.f, 0.f, 0.f};

    #pragma unroll
    for (int kh = 0; kh < 2; kh++) {
        __syncthreads();  // scS/shS visible (kh=0); prev As reads done (kh=1)
        #pragma unroll
        for (int i = 0; i < 4; i++) {
            const int cid = t + 512 * i;
            const int r = cid >> 4, ck = cid & 15;
            const int gr = row0 + r;
            const int kg = kh * 128 + (ck << 3);
            f16x8 v;
            if (gr < n) {
                const float* g = io + (size_t)gr * 256 + kg;
                const float4 f0 = *(const float4*)g;
                const float4 f1 = *(const float4*)(g + 4);
                float f[8] = {f0.x, f0.y, f0.z, f0.w, f1.x, f1.y, f1.z, f1.w};
                #pragma unroll
                for (int j = 0; j < 8; j++)
                    v[j] = (_Float16)fmaxf(f[j] * scS[kg + j] + shS[kg + j], 0.f);
            } else {
                #pragma unroll
                for (int j = 0; j < 8; j++) v[j] = (_Float16)0.f;
            }
            *(f16x8*)&As[r * 128 + ((ck ^ (r & 7)) << 3)] = v;
        }
        #pragma unroll
        for (int cg = 0; cg < 4; cg++) {
            const int st = kh * 4 + cg;
            __syncthreads();  // drains vmcnt: B(st) ready; A visible (cg=0)
            if (st < 7) {
                if (st == 0) STAGE_B4(1, 1);
                else if (st == 1) STAGE_B4(0, 2);
                else if (st == 2) STAGE_B4(1, 3);
                else if (st == 3) STAGE_B4(0, 4);
                else if (st == 4) STAGE_B4(1, 5);
                else if (st == 5) STAGE_B4(0, 6);
                else              STAGE_B4(1, 7);
            }
            #pragma unroll
            for (int s = 0; s < 4; s++) {
                const int r = (wv << 4) + mrow;
                const f16x8 a = *(const f16x8*)&As[r * 128 + ((((s << 2) + quad) ^ (r & 7)) << 3)];
                #pragma unroll
                for (int tc = 0; tc < 4; tc++) {
                    const int rn = (tc << 4) + mrow;
                    const f16x8 b = *(const f16x8*)&Bs[st & 1][rn * 128 + ((((s << 2) + quad) ^ (rn & 7)) << 3)];
                    acc[cg][tc] = __builtin_amdgcn_mfma_f32_16x16x32_f16(a, b, acc[cg][tc], 0, 0, 0);
                }
            }
        }
    }
    __syncthreads();  // all io reads done before in-place writes
    #pragma unroll
    for (int cg = 0; cg < 4; cg++)
        #pragma unroll
        for (int tc = 0; tc < 4; tc++)
            #pragma unroll
            for (int rg = 0; rg < 4; rg++) {
                const int r = row0 + (wv << 4) + (quad << 2) + rg;
                const int c = (cg << 6) + (tc << 4) + mrow;
                if (r < n)
                    io[(size_t)r * 256 + c] = acc[cg][tc][rg] + b2S[c] + x[(size_t)r * 256 + c];
            }
#undef STAGE_B4
}

// ---------------------------------------------------------------------------
extern "C" void kernel_launch(void* const* d_in, const int* in_sizes, int n_in,
                              void* d_out, int out_size, void* d_ws, size_t ws_size,
                              hipStream_t stream)
{
    const float* x     = (const float*)d_in[0];
    const float* Wl    = (const float*)d_in[1];
    const float* bl    = (const float*)d_in[2];
    const float* Wc    = (const float*)d_in[3];
    const float* gamma = (const float*)d_in[4];
    const float* beta  = (const float*)d_in[5];
    const float* W2    = (const float*)d_in[6];
    const float* b2    = (const float*)d_in[7];
    const int* in_idx  = (const int*)d_in[8];
    const int* out_idx = (const int*)d_in[9];

    const int n = in_sizes[0] / 256;        // 200000
    const int M = in_sizes[8] / (4 * 27);   // max pairs per (p,k)

    float* accum = (float*)d_out;

    _Float16* hb = (_Float16*)d_ws;
    const size_t hb_bytes = (size_t)(n + 1) * 256 * sizeof(_Float16);
    _Float16* wct = (_Float16*)((char*)d_ws + hb_bytes);
    const size_t wct_bytes = (size_t)4 * 27 * 4096 * sizeof(_Float16);
    _Float16* wlt = (_Float16*)((char*)wct + wct_bytes);
    _Float16* w2t = (_Float16*)((char*)wlt + 256 * 256 * sizeof(_Float16));
    float* stats = (float*)((char*)w2t + 256 * 256 * sizeof(_Float16));
    float* ssum = stats, *ssq = stats + 256;
    float* scalev = stats + 512, *shiftv = stats + 768;

    hipMemsetAsync(stats, 0, 512 * sizeof(float), stream);
    hipMemsetAsync(hb + (size_t)n * 256, 0, 256 * sizeof(_Float16), stream);

    k0_wct<<<dim3(108), 256, 0, stream>>>(Wc, wct);
    k0_wlt<<<dim3(4, 4), 256, 0, stream>>>(Wl, wlt);
    k0_w2t<<<dim3(4, 4), 256, 0, stream>>>(W2, w2t);

    const int rb2 = (n + 127) >> 7;   // 1563

    k1_gemm_h<<<rb2, 512, 0, stream>>>(x, wlt, bl, hb, n);

    dim3 g2(rb2, 4);
    k2_conv<<<g2, 512, 0, stream>>>(hb, wct, in_idx, out_idx, accum, ssum, ssq, n, M);

    k3_final<<<1, 256, 0, stream>>>(ssum, ssq, gamma, beta, scalev, shiftv, n);

    k4_gemm_out<<<rb2, 512, 0, stream>>>(accum, w2t, b2, x, scalev, shiftv, n);
}